// Round 7
// baseline (721.111 us; speedup 1.0000x reference)
//
#include <hip/hip_runtime.h>
#include <hip/hip_bf16.h>
#include <math.h>

#define M_DIM 32768
#define K_DIM 2048
#define N_DIM 2048
#define NBLK (N_DIM / 128)   // 16 n-blocks

typedef __attribute__((ext_vector_type(8))) short short8;   // 8 bf16 = 4 VGPRs
typedef __attribute__((ext_vector_type(4))) float floatx4;  // MFMA C/D

typedef __attribute__((address_space(1))) const void global_cv;
typedef __attribute__((address_space(3))) void lds_v;

// fp32 -> bf16 bits, round-to-nearest-even
static __device__ __forceinline__ unsigned short f2bf(float f) {
    unsigned u = __builtin_bit_cast(unsigned, f);
    unsigned r = (u + 0x7FFFu + ((u >> 16) & 1u)) >> 16;
    return (unsigned short)r;
}

// ---------------------------------------------------------------------------
// cvt_x: x fp32 (M,K) -> bf16 bits, 16 elems/thread (round 6 ran ~3.7 TB/s
// at 8/thread; more work per thread to push toward BW ceiling).
// ---------------------------------------------------------------------------
__global__ __launch_bounds__(256) void cvt_x(const float* __restrict__ x,
                                             unsigned short* __restrict__ xb) {
    size_t off = ((size_t)blockIdx.x * 256 + threadIdx.x) * 16;
    float4 a = *(const float4*)(x + off);
    float4 b = *(const float4*)(x + off + 4);
    float4 c = *(const float4*)(x + off + 8);
    float4 d = *(const float4*)(x + off + 12);
    short8 p, q;
    p[0] = (short)f2bf(a.x); p[1] = (short)f2bf(a.y);
    p[2] = (short)f2bf(a.z); p[3] = (short)f2bf(a.w);
    p[4] = (short)f2bf(b.x); p[5] = (short)f2bf(b.y);
    p[6] = (short)f2bf(b.z); p[7] = (short)f2bf(b.w);
    q[0] = (short)f2bf(c.x); q[1] = (short)f2bf(c.y);
    q[2] = (short)f2bf(c.z); q[3] = (short)f2bf(c.w);
    q[4] = (short)f2bf(d.x); q[5] = (short)f2bf(d.y);
    q[6] = (short)f2bf(d.z); q[7] = (short)f2bf(d.w);
    *(short8*)(xb + off)     = p;
    *(short8*)(xb + off + 8) = q;
}

// ---------------------------------------------------------------------------
// cvt_wt: W fp32 (K,N) -> Wt bf16 (N,K), 64x64 LDS-tiled transpose.
// ---------------------------------------------------------------------------
__global__ __launch_bounds__(256) void cvt_wt(const float* __restrict__ W,
                                              unsigned short* __restrict__ Wt) {
    __shared__ unsigned short tile[64][65];
    const int t  = threadIdx.x;
    const int nb = blockIdx.x * 64;
    const int kb = blockIdx.y * 64;
#pragma unroll
    for (int i = 0; i < 16; ++i) {
        int e = i * 256 + t;
        int r = e >> 6, c = e & 63;
        tile[r][c] = f2bf(W[(size_t)(kb + r) * N_DIM + nb + c]);
    }
    __syncthreads();
#pragma unroll
    for (int i = 0; i < 16; ++i) {
        int e = i * 256 + t;
        int r = e >> 6, c = e & 63;
        Wt[(size_t)(nb + r) * K_DIM + kb + c] = tile[c][r];
    }
}

// ---------------------------------------------------------------------------
// Fused GEMM(+bias) + per-128-col-block (rowmax, sumexp) partials.
// Round-7: BK=32 (18.25 KB LDS -> round-5 occupancy) + paired-row XOR
// swizzle (round-6's zero-conflict property at 64 B rows):
//   LDS line L = m>>1 (128 B holds row pair), position
//   p(m,kc) = ((m&1)*4 + kc) ^ (L&7);  addr = L*128 + p*16.
// Deposit side realized by source permutation (global_load_lds writes chunk
// c=r*256+t at byte c*16 -> (L,p)=(r*32+(t>>3), t&7); solve for (m,kc)):
//   u = (t&7) ^ ((t>>3)&7);  m = r*64 + 2*(t>>3) + (u>>2);  kc = u&3.
// Verified: deposit(t=20,r=0) byte 320 == read(row 5, quad 2) byte 320.
// Every aligned 8-lane read batch covers all 8 line-positions exactly once.
// ---------------------------------------------------------------------------
__global__ __launch_bounds__(256) void gemm_lse(const unsigned short* __restrict__ xb,
                                                const unsigned short* __restrict__ Wt,
                                                const float* __restrict__ bias,
                                                float2* __restrict__ part) {
    __shared__ unsigned short lds_a[128 * 32];  // swizzled [64 lines][128 B]
    __shared__ unsigned short lds_b[128 * 32];
    __shared__ float red[2][128][2];

    const int t    = threadIdx.x;
    const int w    = t >> 6;
    const int l    = t & 63;
    const int quad = l >> 4;
    const int lrow = l & 15;
    const int m0   = blockIdx.y * 128;
    const int n0   = blockIdx.x * 128;
    const int wm   = (w >> 1) * 64;
    const int wn   = (w & 1) * 64;

    floatx4 acc[4][4] = {};

    // Deposit geometry (per-lane, r-invariant except +64 rows)
    const int u  = (t & 7) ^ ((t >> 3) & 7);
    const int ml = 2 * (t >> 3) + (u >> 2);   // source row 0..63 (round 0)
    const int kc = u & 3;                      // source k-chunk
    const unsigned short* ga = xb + (size_t)(m0 + ml) * K_DIM + kc * 8;
    const unsigned short* gb = Wt + (size_t)(n0 + ml) * K_DIM + kc * 8;
    char* la = (char*)lds_a + t * 16;
    char* lb = (char*)lds_b + t * 16;

    // Fragment read addresses: row_i = (wm|wn)+i*16+lrow, chunk = quad
    const char* aaddr[4];
    const char* baddr[4];
#pragma unroll
    for (int i = 0; i < 4; ++i) {
        int ra = wm + i * 16 + lrow;
        aaddr[i] = (const char*)lds_a + (ra >> 1) * 128 +
                   ((((ra & 1) * 4 + quad) ^ ((ra >> 1) & 7)) * 16);
        int rb = wn + i * 16 + lrow;
        baddr[i] = (const char*)lds_b + (rb >> 1) * 128 +
                   ((((rb & 1) * 4 + quad) ^ ((rb >> 1) & 7)) * 16);
    }

    for (int kt = 0; kt < K_DIM; kt += 32) {
        __builtin_amdgcn_global_load_lds((global_cv*)(ga),                       (lds_v*)(la),        16, 0, 0);
        __builtin_amdgcn_global_load_lds((global_cv*)(ga + (size_t)64 * K_DIM),  (lds_v*)(la + 4096), 16, 0, 0);
        __builtin_amdgcn_global_load_lds((global_cv*)(gb),                       (lds_v*)(lb),        16, 0, 0);
        __builtin_amdgcn_global_load_lds((global_cv*)(gb + (size_t)64 * K_DIM),  (lds_v*)(lb + 4096), 16, 0, 0);
        ga += 32;
        gb += 32;
        __syncthreads();  // drains vmcnt -> tiles deposited

        short8 af[4], bv[4];
#pragma unroll
        for (int im = 0; im < 4; ++im)
            af[im] = *(const short8*)aaddr[im];
#pragma unroll
        for (int in = 0; in < 4; ++in)
            bv[in] = *(const short8*)baddr[in];
#pragma unroll
        for (int im = 0; im < 4; ++im)
#pragma unroll
            for (int in = 0; in < 4; ++in)
                acc[im][in] = __builtin_amdgcn_mfma_f32_16x16x32_bf16(af[im], bv[in], acc[im][in], 0, 0, 0);
        __syncthreads();  // all reads done before next iter's deposits
    }

    // ---- Epilogue (validated): C/D layout col=lrow(n), row=quad*4+reg(m)
    float bvv[4];
#pragma unroll
    for (int in = 0; in < 4; ++in)
        bvv[in] = bias[n0 + wn + in * 16 + lrow];

#pragma unroll
    for (int im = 0; im < 4; ++im) {
#pragma unroll
        for (int r = 0; r < 4; ++r) {
            float v0 = acc[im][0][r] + bvv[0];
            float v1 = acc[im][1][r] + bvv[1];
            float v2 = acc[im][2][r] + bvv[2];
            float v3 = acc[im][3][r] + bvv[3];
            float mx = fmaxf(fmaxf(v0, v1), fmaxf(v2, v3));
#pragma unroll
            for (int s = 1; s < 16; s <<= 1)
                mx = fmaxf(mx, __shfl_xor(mx, s, 64));
            float sm = __expf(v0 - mx) + __expf(v1 - mx) + __expf(v2 - mx) + __expf(v3 - mx);
#pragma unroll
            for (int s = 1; s < 16; s <<= 1)
                sm += __shfl_xor(sm, s, 64);
            if (lrow == im * 4 + r) {
                int row = wm + im * 16 + quad * 4 + r;
                red[w & 1][row][0] = mx;
                red[w & 1][row][1] = sm;
            }
        }
    }
    __syncthreads();
    if (t < 128) {
        float ma = red[0][t][0], sa = red[0][t][1];
        float mb = red[1][t][0], sb = red[1][t][1];
        float mm = fmaxf(ma, mb);
        float ss = sa * __expf(ma - mm) + sb * __expf(mb - mm);
        part[(size_t)blockIdx.x * M_DIM + m0 + t] = make_float2(mm, ss);
    }
}

// ---------------------------------------------------------------------------
// Fallback GEMM (round-4-validated, fp32 inputs, part-only ws).
// ---------------------------------------------------------------------------
__global__ __launch_bounds__(256) void gemm_lse_fb(const float* __restrict__ x,
                                                   const float* __restrict__ W,
                                                   const float* __restrict__ bias,
                                                   float2* __restrict__ part) {
    __shared__ unsigned short lds_a[128 * 32];
    __shared__ unsigned short lds_b[128 * 32];
    __shared__ float red[2][128][2];
    const int t = threadIdx.x, w = t >> 6, l = t & 63, quad = l >> 4, lrow = l & 15;
    const int m0 = blockIdx.y * 128, n0 = blockIdx.x * 128;
    const int wm = (w >> 1) * 64, wn = (w & 1) * 64;
    floatx4 acc[4][4] = {};
    const int ar = t >> 1, ah = (t & 1) * 16;
    const float* gx = x + (size_t)(m0 + ar) * K_DIM + ah;
    const int bn = t & 127, bh = (t >> 7) * 16;
    const float* gw = W + (size_t)bh * N_DIM + n0 + bn;
    for (int kt = 0; kt < K_DIM; kt += 32) {
        float4 xa[4];
#pragma unroll
        for (int q = 0; q < 4; ++q) xa[q] = *(const float4*)(gx + kt + q * 4);
        float wv[16];
#pragma unroll
        for (int j = 0; j < 16; ++j) wv[j] = gw[(size_t)(kt + j) * N_DIM];
        short8 pa0, pa1, pb0, pb1;
#pragma unroll
        for (int j = 0; j < 4; ++j) {
            pa0[j] = (short)f2bf(((const float*)&xa[0])[j]);
            pa0[j + 4] = (short)f2bf(((const float*)&xa[1])[j]);
            pa1[j] = (short)f2bf(((const float*)&xa[2])[j]);
            pa1[j + 4] = (short)f2bf(((const float*)&xa[3])[j]);
        }
#pragma unroll
        for (int j = 0; j < 8; ++j) { pb0[j] = (short)f2bf(wv[j]); pb1[j] = (short)f2bf(wv[j + 8]); }
        __syncthreads();
        *(short8*)&lds_a[ar * 32 + ah] = pa0;
        *(short8*)&lds_a[ar * 32 + ah + 8] = pa1;
        *(short8*)&lds_b[bn * 32 + bh] = pb0;
        *(short8*)&lds_b[bn * 32 + bh + 8] = pb1;
        __syncthreads();
        short8 af[4], bf[4];
#pragma unroll
        for (int im = 0; im < 4; ++im)
            af[im] = *(const short8*)((const char*)lds_a + (wm + im * 16 + lrow) * 64 + quad * 16);
#pragma unroll
        for (int in = 0; in < 4; ++in)
            bf[in] = *(const short8*)((const char*)lds_b + (wn + in * 16 + lrow) * 64 + quad * 16);
#pragma unroll
        for (int im = 0; im < 4; ++im)
#pragma unroll
            for (int in = 0; in < 4; ++in)
                acc[im][in] = __builtin_amdgcn_mfma_f32_16x16x32_bf16(af[im], bf[in], acc[im][in], 0, 0, 0);
    }
    float bvv[4];
#pragma unroll
    for (int in = 0; in < 4; ++in) bvv[in] = bias[n0 + wn + in * 16 + lrow];
#pragma unroll
    for (int im = 0; im < 4; ++im) {
#pragma unroll
        for (int r = 0; r < 4; ++r) {
            float v0 = acc[im][0][r] + bvv[0], v1 = acc[im][1][r] + bvv[1];
            float v2 = acc[im][2][r] + bvv[2], v3 = acc[im][3][r] + bvv[3];
            float mx = fmaxf(fmaxf(v0, v1), fmaxf(v2, v3));
#pragma unroll
            for (int s = 1; s < 16; s <<= 1) mx = fmaxf(mx, __shfl_xor(mx, s, 64));
            float sm = __expf(v0 - mx) + __expf(v1 - mx) + __expf(v2 - mx) + __expf(v3 - mx);
#pragma unroll
            for (int s = 1; s < 16; s <<= 1) sm += __shfl_xor(sm, s, 64);
            if (lrow == im * 4 + r) {
                int row = wm + im * 16 + quad * 4 + r;
                red[w & 1][row][0] = mx;
                red[w & 1][row][1] = sm;
            }
        }
    }
    __syncthreads();
    if (t < 128) {
        float ma = red[0][t][0], sa = red[0][t][1];
        float mb = red[1][t][0], sb = red[1][t][1];
        float mm = fmaxf(ma, mb);
        float ss = sa * __expf(ma - mm) + sb * __expf(mb - mm);
        part[(size_t)blockIdx.x * M_DIM + m0 + t] = make_float2(mm, ss);
    }
}

// ---------------------------------------------------------------------------
// Merge NBLK partials per row, logsumexp, leaky x2, erf-GELU x2. FLOAT out.
// ---------------------------------------------------------------------------
__global__ __launch_bounds__(256) void lse_final(const float2* __restrict__ part,
                                                 float* __restrict__ out) {
    const int r = blockIdx.x * 256 + threadIdx.x;
    float2 p[NBLK];
    float mm = -INFINITY;
#pragma unroll
    for (int nb = 0; nb < NBLK; ++nb) {
        p[nb] = part[(size_t)nb * M_DIM + r];
        mm = fmaxf(mm, p[nb].x);
    }
    float ss = 0.f;
#pragma unroll
    for (int nb = 0; nb < NBLK; ++nb)
        ss += p[nb].y * __expf(p[nb].x - mm);

    float z;
    if (isnan(mm)) {
        z = 12345.0f;               // tripwire A (inert when correct)
    } else if (!(ss > 0.f)) {
        z = mm;                     // tripwire B (inert when correct)
    } else {
        z = mm + logf(ss);
    }
    z = z > 0.f ? z : 0.01f * z;
    z = z > 0.f ? z : 0.01f * z;
    z = 0.5f * z * (1.f + erff(z * 0.70710678118654752f));
    z = 0.5f * z * (1.f + erff(z * 0.70710678118654752f));
    out[r] = z;
}

// ---------------------------------------------------------------------------
extern "C" void kernel_launch(void* const* d_in, const int* in_sizes, int n_in,
                              void* d_out, int out_size, void* d_ws, size_t ws_size,
                              hipStream_t stream) {
    const float* x    = (const float*)d_in[0];
    const float* W    = (const float*)d_in[1];
    const float* bias = (const float*)d_in[2];
    float* out = (float*)d_out;

    const size_t xb_bytes   = (size_t)M_DIM * K_DIM * 2;  // 134 MB
    const size_t wt_bytes   = (size_t)N_DIM * K_DIM * 2;  //   8 MB
    const size_t part_bytes = (size_t)NBLK * M_DIM * 8;   //   4 MB

    if (ws_size >= xb_bytes + wt_bytes + part_bytes) {
        unsigned short* xb = (unsigned short*)d_ws;
        unsigned short* Wt = (unsigned short*)((char*)d_ws + xb_bytes);
        float2* part = (float2*)((char*)d_ws + xb_bytes + wt_bytes);
        cvt_x<<<(int)((size_t)M_DIM * K_DIM / (16 * 256)), 256, 0, stream>>>(x, xb);
        cvt_wt<<<dim3(N_DIM / 64, K_DIM / 64), 256, 0, stream>>>(W, Wt);
        gemm_lse<<<dim3(N_DIM / 128, M_DIM / 128), 256, 0, stream>>>(xb, Wt, bias, part);
        lse_final<<<M_DIM / 256, 256, 0, stream>>>(part, out);
    } else {
        float2* part = (float2*)d_ws;
        gemm_lse_fb<<<dim3(N_DIM / 128, M_DIM / 128), 256, 0, stream>>>(x, W, bias, part);
        lse_final<<<M_DIM / 256, 256, 0, stream>>>(part, out);
    }
}